// Round 2
// baseline (322.970 us; speedup 1.0000x reference)
//
#include <hip/hip_runtime.h>

// MultiHeadEMA: out[b,l,d] = omega[d]*x[b,l,d] + sum_n gc[d,n] * u_n[b,l,d]
//   u_n[l] = q_n * u_n[l-1] + x[l],  u_n[-1] = 0
//   q_n  = 1 - sigmoid(delta)*sigmoid(alpha)
//   gc_n = sigmoid(delta)*beta * gamma * sqrt(1/N)
// All fp32 in, fp32 out (reference computes in float32 throughout).
#define BB 8
#define LL 4096
#define DD 1024
#define NN 16
#define GG 32            // number of L-chunks
#define CC (LL / GG)     // 128 steps per chunk

__device__ __forceinline__ float sigmoid_precise(float v) {
    return 1.0f / (1.0f + expf(-v));
}

// Kernel 1: per-chunk local scan from zero state; write end states E[b][g][n][d].
__global__ __launch_bounds__(64) void ema_chunk_states(
    const float* __restrict__ x,
    const float* __restrict__ delta,
    const float* __restrict__ alpha,
    float* __restrict__ E)
{
    const int lane = threadIdx.x;                 // 0..63 -> consecutive d (coalesced)
    const int g    = blockIdx.x;
    const int d    = blockIdx.y * 64 + lane;
    const int b    = blockIdx.z;

    float q[NN];
#pragma unroll
    for (int n = 0; n < NN; ++n) {
        float p = sigmoid_precise(delta[d * NN + n]);
        float a = sigmoid_precise(alpha[d * NN + n]);
        q[n] = 1.0f - p * a;
    }

    float u[NN];
#pragma unroll
    for (int n = 0; n < NN; ++n) u[n] = 0.0f;

    const float* xp = x + ((size_t)b * LL + (size_t)g * CC) * DD + d;
#pragma unroll 4
    for (int i = 0; i < CC; ++i) {
        float xv = xp[(size_t)i * DD];
#pragma unroll
        for (int n = 0; n < NN; ++n)
            u[n] = fmaf(q[n], u[n], xv);
    }

    float* Ep = E + (((size_t)b * GG + g) * NN) * DD + d;
#pragma unroll
    for (int n = 0; n < NN; ++n)
        Ep[(size_t)n * DD] = u[n];
}

// Kernel 2: rebuild carry-in from previous chunks' end states, rescan chunk,
// emit fp32 output with residual fused.
__global__ __launch_bounds__(64) void ema_final(
    const float* __restrict__ x,
    const float* __restrict__ delta,
    const float* __restrict__ alpha,
    const float* __restrict__ beta,
    const float* __restrict__ gamma,
    const float* __restrict__ omega,
    const float* __restrict__ E,
    float* __restrict__ out)
{
    const int lane = threadIdx.x;
    const int g    = blockIdx.x;
    const int d    = blockIdx.y * 64 + lane;
    const int b    = blockIdx.z;

    float q[NN], gc[NN];
#pragma unroll
    for (int n = 0; n < NN; ++n) {
        float p = sigmoid_precise(delta[d * NN + n]);
        float a = sigmoid_precise(alpha[d * NN + n]);
        q[n]  = 1.0f - p * a;
        gc[n] = p * beta[d * NN + n] * gamma[d * NN + n] * 0.25f; // scale = sqrt(1/16)
    }

    // Carry-in: u = sum_{g'<g} (q^CC)^(g-1-g') * E[b,g',n,d]
    float u[NN];
#pragma unroll
    for (int n = 0; n < NN; ++n) u[n] = 0.0f;
    if (g > 0) {                                  // block-uniform branch
        float Q[NN];
#pragma unroll
        for (int n = 0; n < NN; ++n) Q[n] = powf(q[n], (float)CC);
        for (int gp = 0; gp < g; ++gp) {
            const float* Ep = E + (((size_t)b * GG + gp) * NN) * DD + d;
#pragma unroll
            for (int n = 0; n < NN; ++n)
                u[n] = fmaf(Q[n], u[n], Ep[(size_t)n * DD]);
        }
    }

    const float om = omega[d];
    const float* xp = x + ((size_t)b * LL + (size_t)g * CC) * DD + d;
    float* op = out + ((size_t)b * LL + (size_t)g * CC) * DD + d;

#pragma unroll 4
    for (int i = 0; i < CC; ++i) {
        float xv = xp[(size_t)i * DD];
        float acc = om * xv;
#pragma unroll
        for (int n = 0; n < NN; ++n) {
            u[n] = fmaf(q[n], u[n], xv);
            acc  = fmaf(gc[n], u[n], acc);
        }
        op[(size_t)i * DD] = acc;
    }
}

extern "C" void kernel_launch(void* const* d_in, const int* in_sizes, int n_in,
                              void* d_out, int out_size, void* d_ws, size_t ws_size,
                              hipStream_t stream) {
    const float* x     = (const float*)d_in[0];
    const float* delta = (const float*)d_in[1];
    const float* alpha = (const float*)d_in[2];
    const float* beta  = (const float*)d_in[3];
    const float* gamma = (const float*)d_in[4];
    const float* omega = (const float*)d_in[5];
    float* out = (float*)d_out;
    float* E = (float*)d_ws;   // B*G*N*D floats = 16 MB

    dim3 grid(GG, DD / 64, BB);
    dim3 block(64);
    hipLaunchKernelGGL(ema_chunk_states, grid, block, 0, stream,
                       x, delta, alpha, E);
    hipLaunchKernelGGL(ema_final, grid, block, 0, stream,
                       x, delta, alpha, beta, gamma, omega, E, out);
}

// Round 3
// 306.465 us; speedup vs baseline: 1.0539x; 1.0539x over previous
//
#include <hip/hip_runtime.h>

// MultiHeadEMA: out[b,l,d] = omega[d]*x[b,l,d] + sum_n gc[d,n] * u_n[b,l,d]
//   u_n[l] = q_n * u_n[l-1] + x[l],  u_n[-1] = 0
//   q_n  = 1 - sigmoid(delta)*sigmoid(alpha)
//   gc_n = sigmoid(delta)*beta * gamma * sqrt(1/N)
// All fp32 in, fp32 out.
#define BB 8
#define LL 4096
#define DD 1024
#define NN 16
#define GG 32            // number of L-chunks
#define CC (LL / GG)     // 128 steps per chunk
#define UF 8             // load batch (outstanding 256B loads per wave)

__device__ __forceinline__ float sigmoid_precise(float v) {
    return 1.0f / (1.0f + expf(-v));
}

// Kernel 1: per-chunk local scan from zero state; write end states E[b][g][n][d].
__global__ __launch_bounds__(256) void ema_chunk_states(
    const float* __restrict__ x,
    const float* __restrict__ delta,
    const float* __restrict__ alpha,
    float* __restrict__ E)
{
    const int g = blockIdx.x;
    const int d = blockIdx.y * 256 + threadIdx.x;   // consecutive d -> coalesced
    const int b = blockIdx.z;

    float q[NN];
#pragma unroll
    for (int n = 0; n < NN; ++n) {
        float p = sigmoid_precise(delta[d * NN + n]);
        float a = sigmoid_precise(alpha[d * NN + n]);
        q[n] = 1.0f - p * a;
    }

    float u[NN];
#pragma unroll
    for (int n = 0; n < NN; ++n) u[n] = 0.0f;

    const float* xp = x + ((size_t)b * LL + (size_t)g * CC) * DD + d;
    for (int ii = 0; ii < CC; ii += UF) {
        float xv[UF];
#pragma unroll
        for (int j = 0; j < UF; ++j)
            xv[j] = xp[(size_t)(ii + j) * DD];       // 8 loads issued back-to-back
#pragma unroll
        for (int j = 0; j < UF; ++j) {
#pragma unroll
            for (int n = 0; n < NN; ++n)
                u[n] = fmaf(q[n], u[n], xv[j]);
        }
    }

    float* Ep = E + (((size_t)b * GG + g) * NN) * DD + d;
#pragma unroll
    for (int n = 0; n < NN; ++n)
        Ep[(size_t)n * DD] = u[n];
}

// Kernel 2: rebuild carry-in from previous chunks' end states, rescan chunk,
// emit fp32 output with residual fused.
__global__ __launch_bounds__(256) void ema_final(
    const float* __restrict__ x,
    const float* __restrict__ delta,
    const float* __restrict__ alpha,
    const float* __restrict__ beta,
    const float* __restrict__ gamma,
    const float* __restrict__ omega,
    const float* __restrict__ E,
    float* __restrict__ out)
{
    const int g = blockIdx.x;
    const int d = blockIdx.y * 256 + threadIdx.x;
    const int b = blockIdx.z;

    float q[NN], gc[NN];
#pragma unroll
    for (int n = 0; n < NN; ++n) {
        float p = sigmoid_precise(delta[d * NN + n]);
        float a = sigmoid_precise(alpha[d * NN + n]);
        q[n]  = 1.0f - p * a;
        gc[n] = p * beta[d * NN + n] * gamma[d * NN + n] * 0.25f; // scale = sqrt(1/16)
    }

    // Carry-in: u = sum_{g'<g} (q^CC)^(g-1-g') * E[b,g',n,d]
    float u[NN];
#pragma unroll
    for (int n = 0; n < NN; ++n) u[n] = 0.0f;
    if (g > 0) {                                  // block-uniform branch
        float Q[NN];
#pragma unroll
        for (int n = 0; n < NN; ++n) Q[n] = powf(q[n], (float)CC);
        for (int gp = 0; gp < g; ++gp) {
            const float* Ep = E + (((size_t)b * GG + gp) * NN) * DD + d;
#pragma unroll
            for (int n = 0; n < NN; ++n)
                u[n] = fmaf(Q[n], u[n], Ep[(size_t)n * DD]);
        }
    }

    const float om = omega[d];
    const float* xp = x + ((size_t)b * LL + (size_t)g * CC) * DD + d;
    float* op = out + ((size_t)b * LL + (size_t)g * CC) * DD + d;

    for (int ii = 0; ii < CC; ii += UF) {
        float xv[UF];
#pragma unroll
        for (int j = 0; j < UF; ++j)
            xv[j] = __builtin_nontemporal_load(&xp[(size_t)(ii + j) * DD]);
#pragma unroll
        for (int j = 0; j < UF; ++j) {
            float xvj = xv[j];
            // 4 independent accumulator chains (break the 16-deep fma chain)
            float a0 = om * xvj, a1 = 0.0f, a2 = 0.0f, a3 = 0.0f;
#pragma unroll
            for (int n = 0; n < NN; n += 4) {
                u[n + 0] = fmaf(q[n + 0], u[n + 0], xvj);
                u[n + 1] = fmaf(q[n + 1], u[n + 1], xvj);
                u[n + 2] = fmaf(q[n + 2], u[n + 2], xvj);
                u[n + 3] = fmaf(q[n + 3], u[n + 3], xvj);
                a0 = fmaf(gc[n + 0], u[n + 0], a0);
                a1 = fmaf(gc[n + 1], u[n + 1], a1);
                a2 = fmaf(gc[n + 2], u[n + 2], a2);
                a3 = fmaf(gc[n + 3], u[n + 3], a3);
            }
            float acc = (a0 + a1) + (a2 + a3);
            __builtin_nontemporal_store(acc, &op[(size_t)(ii + j) * DD]);
        }
    }
}

extern "C" void kernel_launch(void* const* d_in, const int* in_sizes, int n_in,
                              void* d_out, int out_size, void* d_ws, size_t ws_size,
                              hipStream_t stream) {
    const float* x     = (const float*)d_in[0];
    const float* delta = (const float*)d_in[1];
    const float* alpha = (const float*)d_in[2];
    const float* beta  = (const float*)d_in[3];
    const float* gamma = (const float*)d_in[4];
    const float* omega = (const float*)d_in[5];
    float* out = (float*)d_out;
    float* E = (float*)d_ws;   // B*G*N*D floats = 16 MB

    dim3 grid(GG, DD / 256, BB);
    dim3 block(256);
    hipLaunchKernelGGL(ema_chunk_states, grid, block, 0, stream,
                       x, delta, alpha, E);
    hipLaunchKernelGGL(ema_final, grid, block, 0, stream,
                       x, delta, alpha, beta, gamma, omega, E, out);
}

// Round 4
// 295.230 us; speedup vs baseline: 1.0940x; 1.0381x over previous
//
#include <hip/hip_runtime.h>

// MultiHeadEMA: out[b,l,d] = omega[d]*x[b,l,d] + sum_n gc[d,n] * u_n[b,l,d]
//   u_n[l] = q_n * u_n[l-1] + x[l],  u_n[-1] = 0
//   q_n  = 1 - sigmoid(delta)*sigmoid(alpha)
//   gc_n = sigmoid(delta)*beta * gamma * sqrt(1/N)
// All fp32 in, fp32 out.
//
// 3-kernel chained scan:
//   k1: per-chunk local scan from zero state -> E[b][g][n][d]
//   k2: per-(b,n,d) sequential scan over g, in place: S[g] = E[g] + q^C * S[g-1]
//   k3: chunk rescan seeded with carry-in S[g-1], fused residual, write out
#define BB 8
#define LL 4096
#define DD 1024
#define NN 16
#define UF 8             // load batch (outstanding 256B loads per wave)

__device__ __forceinline__ float sigmoid_precise(float v) {
    return 1.0f / (1.0f + expf(-v));
}

// Kernel 1: per-chunk local scan from zero state; write end states E[b][g][n][d].
template <int G_>
__global__ __launch_bounds__(256) void ema_chunk_states(
    const float* __restrict__ x,
    const float* __restrict__ delta,
    const float* __restrict__ alpha,
    float* __restrict__ E)
{
    constexpr int C_ = LL / G_;
    const int g = blockIdx.x;
    const int d = blockIdx.y * 256 + threadIdx.x;   // consecutive d -> coalesced
    const int b = blockIdx.z;

    float q[NN];
#pragma unroll
    for (int n = 0; n < NN; ++n) {
        float p = sigmoid_precise(delta[d * NN + n]);
        float a = sigmoid_precise(alpha[d * NN + n]);
        q[n] = 1.0f - p * a;
    }

    float u[NN];
#pragma unroll
    for (int n = 0; n < NN; ++n) u[n] = 0.0f;

    const float* xp = x + ((size_t)b * LL + (size_t)g * C_) * DD + d;
    for (int ii = 0; ii < C_; ii += UF) {
        float xv[UF];
#pragma unroll
        for (int j = 0; j < UF; ++j)
            xv[j] = xp[(size_t)(ii + j) * DD];       // batch: 8 loads in flight
#pragma unroll
        for (int j = 0; j < UF; ++j) {
#pragma unroll
            for (int n = 0; n < NN; ++n)
                u[n] = fmaf(q[n], u[n], xv[j]);
        }
    }

    float* Ep = E + (((size_t)b * G_ + g) * NN) * DD + d;
#pragma unroll
    for (int n = 0; n < NN; ++n)
        Ep[(size_t)n * DD] = u[n];
}

// Kernel 2: in-place inclusive scan of chunk states across g.
// One thread per (b,n,d): S[g] = E[g] + q^C * S[g-1].
template <int G_>
__global__ __launch_bounds__(256) void ema_carry_scan(
    const float* __restrict__ delta,
    const float* __restrict__ alpha,
    float* __restrict__ E)
{
    constexpr int C_ = LL / G_;
    const int t = blockIdx.x * 256 + threadIdx.x;    // B*N*D threads
    const int d = t & (DD - 1);
    const int n = (t >> 10) & (NN - 1);
    const int b = t >> 14;

    const float p = sigmoid_precise(delta[d * NN + n]);
    const float a = sigmoid_precise(alpha[d * NN + n]);
    const float q = 1.0f - p * a;
    const float Qc = powf(q, (float)C_);

    float* Ep = E + (((size_t)b * G_) * NN + n) * DD + d;
    const size_t gstride = (size_t)NN * DD;

    float u = 0.0f;
    for (int gg = 0; gg < G_; gg += UF) {
        float ev[UF], sv[UF];
#pragma unroll
        for (int j = 0; j < UF; ++j)
            ev[j] = Ep[(size_t)(gg + j) * gstride];
#pragma unroll
        for (int j = 0; j < UF; ++j) {
            u = fmaf(Qc, u, ev[j]);
            sv[j] = u;
        }
#pragma unroll
        for (int j = 0; j < UF; ++j)
            Ep[(size_t)(gg + j) * gstride] = sv[j];
    }
}

// Kernel 3: rescan chunk seeded with carry-in S[g-1]; fuse residual; write out.
template <int G_>
__global__ __launch_bounds__(256) void ema_final(
    const float* __restrict__ x,
    const float* __restrict__ delta,
    const float* __restrict__ alpha,
    const float* __restrict__ beta,
    const float* __restrict__ gamma,
    const float* __restrict__ omega,
    const float* __restrict__ S,      // scanned states from k2
    float* __restrict__ out)
{
    constexpr int C_ = LL / G_;
    const int g = blockIdx.x;
    const int d = blockIdx.y * 256 + threadIdx.x;
    const int b = blockIdx.z;

    float q[NN], gc[NN];
#pragma unroll
    for (int n = 0; n < NN; ++n) {
        float p = sigmoid_precise(delta[d * NN + n]);
        float a = sigmoid_precise(alpha[d * NN + n]);
        q[n]  = 1.0f - p * a;
        gc[n] = p * beta[d * NN + n] * gamma[d * NN + n] * 0.25f; // scale = sqrt(1/16)
    }

    float u[NN];
    if (g > 0) {                                  // block-uniform branch
        const float* Sp = S + (((size_t)b * G_ + (g - 1)) * NN) * DD + d;
#pragma unroll
        for (int n = 0; n < NN; ++n)
            u[n] = Sp[(size_t)n * DD];
    } else {
#pragma unroll
        for (int n = 0; n < NN; ++n) u[n] = 0.0f;
    }

    const float om = omega[d];
    const float* xp = x + ((size_t)b * LL + (size_t)g * C_) * DD + d;
    float* op = out + ((size_t)b * LL + (size_t)g * C_) * DD + d;

    for (int ii = 0; ii < C_; ii += UF) {
        float xv[UF];
#pragma unroll
        for (int j = 0; j < UF; ++j)
            xv[j] = xp[(size_t)(ii + j) * DD];
#pragma unroll
        for (int j = 0; j < UF; ++j) {
            float xvj = xv[j];
            float a0 = om * xvj, a1 = 0.0f, a2 = 0.0f, a3 = 0.0f;
#pragma unroll
            for (int n = 0; n < NN; n += 4) {
                u[n + 0] = fmaf(q[n + 0], u[n + 0], xvj);
                u[n + 1] = fmaf(q[n + 1], u[n + 1], xvj);
                u[n + 2] = fmaf(q[n + 2], u[n + 2], xvj);
                u[n + 3] = fmaf(q[n + 3], u[n + 3], xvj);
                a0 = fmaf(gc[n + 0], u[n + 0], a0);
                a1 = fmaf(gc[n + 1], u[n + 1], a1);
                a2 = fmaf(gc[n + 2], u[n + 2], a2);
                a3 = fmaf(gc[n + 3], u[n + 3], a3);
            }
            op[(size_t)(ii + j) * DD] = (a0 + a1) + (a2 + a3);
        }
    }
}

template <int G_>
static void launch_all(const float* x, const float* delta, const float* alpha,
                       const float* beta, const float* gamma, const float* omega,
                       float* out, float* E, hipStream_t stream)
{
    dim3 block(256);
    dim3 grid13(G_, DD / 256, BB);
    dim3 grid2((BB * NN * DD) / 256);
    hipLaunchKernelGGL(ema_chunk_states<G_>, grid13, block, 0, stream,
                       x, delta, alpha, E);
    hipLaunchKernelGGL(ema_carry_scan<G_>, grid2, block, 0, stream,
                       delta, alpha, E);
    hipLaunchKernelGGL(ema_final<G_>, grid13, block, 0, stream,
                       x, delta, alpha, beta, gamma, omega, E, out);
}

extern "C" void kernel_launch(void* const* d_in, const int* in_sizes, int n_in,
                              void* d_out, int out_size, void* d_ws, size_t ws_size,
                              hipStream_t stream) {
    const float* x     = (const float*)d_in[0];
    const float* delta = (const float*)d_in[1];
    const float* alpha = (const float*)d_in[2];
    const float* beta  = (const float*)d_in[3];
    const float* gamma = (const float*)d_in[4];
    const float* omega = (const float*)d_in[5];
    float* out = (float*)d_out;
    float* E = (float*)d_ws;

    const size_t need64 = (size_t)BB * 64 * NN * DD * sizeof(float);   // 32 MB
    if (ws_size >= need64)
        launch_all<64>(x, delta, alpha, beta, gamma, omega, out, E, stream);
    else
        launch_all<32>(x, delta, alpha, beta, gamma, omega, out, E, stream);
}